// Round 4
// baseline (203.389 us; speedup 1.0000x reference)
//
#include <hip/hip_runtime.h>
#include <hip/hip_bf16.h>
#include <cmath>

#define BS 8
#define SEQ 16384
#define D 128
#define NH 8
#define HD 16
#define EPS_ 1e-5f

#define CH 64                   // tokens per chunk
// passA: 2 chunks/block -> 128 tok/block, 1024 blocks
#define NCHK_A 2
#define BPB_A (SEQ/(CH*NCHK_A))   // 128
// passB: 1 chunk/block -> 64 tok/block, 2048 blocks
#define BPB_B (SEQ/CH)            // 256

typedef __attribute__((ext_vector_type(8))) short bf16x8;
typedef __attribute__((ext_vector_type(4))) float f32x4;
typedef __attribute__((ext_vector_type(4))) unsigned int u32x4;
typedef __attribute__((ext_vector_type(2))) unsigned int u32x2;

#define MFMA16(a,b,c) __builtin_amdgcn_mfma_f32_16x16x32_bf16(a,b,c,0,0,0)

__device__ __forceinline__ unsigned short bf16rn(float x){
    union { __hip_bfloat16 h; unsigned short u; } v;
    v.h = __float2bfloat16(x);
    return v.u;
}
__device__ __forceinline__ float bf16tof(short u){
    union { unsigned int u; float f; } v;
    v.u = ((unsigned int)(unsigned short)u) << 16;
    return v.f;
}
__device__ __forceinline__ unsigned int cvt2(float a, float b){
    union { __hip_bfloat162 h; unsigned int u; } v;
    v.h = __float22bfloat162_rn(make_float2(a, b));
    return v.u;
}
// natural [64 tok][128 col] bf16 LDS; XOR-swizzle, 16B granule
__device__ __forceinline__ int swzQ(int tok, int col){ return (tok*128 + col) ^ ((tok&7)<<3); }
// transposed [256 col][64 tok] bf16 LDS
__device__ __forceinline__ int swzT(int col, int tok){ return (col*64 + tok) ^ ((col&7)<<3); }

// ---------------------------------------------------------------------------
// Weight pre-pack (unchanged from round 3)
// ---------------------------------------------------------------------------
__global__ __launch_bounds__(256) void packW(
    const float* __restrict__ Wk, const float* __restrict__ Wv,
    const float* __restrict__ Wq, const float* __restrict__ Wo,
    short* __restrict__ WB, short* __restrict__ WqA, short* __restrict__ WoA)
{
    int e = blockIdx.x * 256 + threadIdx.x;     // 0..8191
    short v8[8];
    if (e < 4096) {
        int nt = e >> 8, kt = (e >> 6) & 3, l = e & 63;
        int col = nt * 16 + (l & 15);
        const float* W = (col < 128) ? Wk : Wv;
        int cc = col & 127;
#pragma unroll
        for (int j = 0; j < 8; ++j) {
            int k = kt*32 + (l>>4)*8 + j;
            v8[j] = (short)bf16rn(W[k*D + cc]);
        }
        u32x4 p = u32x4{ (unsigned)(unsigned short)v8[0] | ((unsigned)(unsigned short)v8[1]<<16),
                         (unsigned)(unsigned short)v8[2] | ((unsigned)(unsigned short)v8[3]<<16),
                         (unsigned)(unsigned short)v8[4] | ((unsigned)(unsigned short)v8[5]<<16),
                         (unsigned)(unsigned short)v8[6] | ((unsigned)(unsigned short)v8[7]<<16) };
        *(u32x4*)&WB[((nt*4 + kt)*64 + l)*8] = p;
    } else {
        int e2 = e - 4096;
        const float* W = (e2 < 2048) ? Wq : Wo;
        short* dst = (e2 < 2048) ? WqA : WoA;
        e2 &= 2047;
        int mt = e2 >> 8, kt = (e2 >> 6) & 3, l = e2 & 63;
        int m = mt*16 + (l & 15);
#pragma unroll
        for (int j = 0; j < 8; ++j) {
            int k = kt*32 + (l>>4)*8 + j;
            v8[j] = (short)bf16rn(W[k*D + m]);
        }
        u32x4 p = u32x4{ (unsigned)(unsigned short)v8[0] | ((unsigned)(unsigned short)v8[1]<<16),
                         (unsigned)(unsigned short)v8[2] | ((unsigned)(unsigned short)v8[3]<<16),
                         (unsigned)(unsigned short)v8[4] | ((unsigned)(unsigned short)v8[5]<<16),
                         (unsigned)(unsigned short)v8[6] | ((unsigned)(unsigned short)v8[7]<<16) };
        *(u32x4*)&dst[((mt*4 + kt)*64 + l)*8] = p;
    }
}

// ---------------------------------------------------------------------------
// Pass A: k,v projections (MFMA) + phi_k; KV & Ksum via MFMA over tokens.
// 1024 blocks x 128 tokens. LDS 48KB -> 3 blocks/CU.
// ---------------------------------------------------------------------------
__global__ __launch_bounds__(256, 3) void passA(
    const float* __restrict__ Q,
    const float* __restrict__ bk, const float* __restrict__ bv,
    const short* __restrict__ WB,
    float* __restrict__ KV, float* __restrict__ Ksum)
{
    __shared__ __align__(16) short Qlds[64*128];   // 16 KB
    __shared__ __align__(16) short TL[256*64];     // 32 KB: [kcol|vcol][tok]

    const int t = threadIdx.x;
    const int w = t >> 6, l = t & 63;
    const int b  = blockIdx.x / BPB_A;
    const int bb = blockIdx.x % BPB_A;
    const long base = (long)b * SEQ + (long)bb * (CH * NCHK_A);

    bf16x8 wb[4][4];
#pragma unroll
    for (int ntl = 0; ntl < 4; ++ntl)
#pragma unroll
        for (int kt = 0; kt < 4; ++kt)
            wb[ntl][kt] = *(const bf16x8*)&WB[(((w*4+ntl)*4 + kt)*64 + l)*8];

    float bias[4];
#pragma unroll
    for (int ntl = 0; ntl < 4; ++ntl) {
        int col = (w*4+ntl)*16 + (l & 15);
        bias[ntl] = (col < 128) ? bk[col] : bv[col-128];
    }

    union { u32x4 u; bf16x8 h; } onesu;
    unsigned ov = ((l & 15) == 0) ? 0x3F803F80u : 0u;
    onesu.u = u32x4{ov, ov, ov, ov};
    const bf16x8 bones = onesu.h;

    const int h0 = w * 2;
    const f32x4 z4 = {0.f, 0.f, 0.f, 0.f};
    f32x4 kvacc[2] = {z4, z4};
    f32x4 ksacc[2] = {z4, z4};

    for (int c = 0; c < NCHK_A; ++c) {
        const long tok0 = base + (long)c * CH;

        // --- stage Q chunk -> bf16 LDS ---
#pragma unroll
        for (int i = 0; i < 4; ++i) {
            int lin = i*256 + t;
            int row = lin >> 4;
            int c0  = (lin & 15) * 8;
            const float4* gp = (const float4*)&Q[(tok0 + row)*D + c0];
            float4 a = gp[0], d4 = gp[1];
            u32x4 p = u32x4{cvt2(a.x,a.y), cvt2(a.z,a.w), cvt2(d4.x,d4.y), cvt2(d4.z,d4.w)};
            *(u32x4*)&Qlds[swzQ(row, c0)] = p;
        }
        __syncthreads();                           // bar1: Qlds ready

        // --- k|v projection per mt; phi; write transposed TL ---
#pragma unroll
        for (int mt = 0; mt < 4; ++mt) {
            bf16x8 af[4];
#pragma unroll
            for (int kt = 0; kt < 4; ++kt)
                af[kt] = *(bf16x8*)&Qlds[swzQ(mt*16 + (l&15), kt*32 + (l>>4)*8)];
#pragma unroll
            for (int ntl = 0; ntl < 4; ++ntl) {
                f32x4 acc = f32x4{bias[ntl], bias[ntl], bias[ntl], bias[ntl]};
#pragma unroll
                for (int kt = 0; kt < 4; ++kt)
                    acc = MFMA16(af[kt], wb[ntl][kt], acc);
                int colg = (w*4+ntl)*16 + (l & 15);
                if (colg < 128) {                  // wave-uniform (w<2)
#pragma unroll
                    for (int r = 0; r < 4; ++r)
                        acc[r] = (acc[r] > 0.f) ? (acc[r] + 1.f) : __expf(acc[r]);
                }
                int tokb = mt*16 + (l>>4)*4;
                u32x2 p = u32x2{cvt2(acc[0], acc[1]), cvt2(acc[2], acc[3])};
                *(u32x2*)&TL[swzT(colg, tokb)] = p;
            }
        }
        __syncthreads();                           // bar2: TL ready

        // --- KV & Ksum MFMA (2 heads per wave) ---
#pragma unroll
        for (int hh = 0; hh < 2; ++hh) {
            int h = h0 + hh;
#pragma unroll
            for (int k2 = 0; k2 < 2; ++k2) {
                bf16x8 afk = *(bf16x8*)&TL[swzT(h*16 + (l&15),       k2*32 + (l>>4)*8)];
                bf16x8 bfv = *(bf16x8*)&TL[swzT(128 + h*16 + (l&15), k2*32 + (l>>4)*8)];
                kvacc[hh] = MFMA16(afk, bfv,  kvacc[hh]);
                ksacc[hh] = MFMA16(afk, bones, ksacc[hh]);
            }
        }
    }

#pragma unroll
    for (int hh = 0; hh < 2; ++hh) {
        int h = h0 + hh;
#pragma unroll
        for (int r = 0; r < 4; ++r) {
            int d = (l>>4)*4 + r, m = l & 15;
            atomicAdd(&KV[((b*NH + h)*HD + d)*HD + m], kvacc[hh][r]);
        }
        if ((l & 15) == 0) {
#pragma unroll
            for (int r = 0; r < 4; ++r)
                atomicAdd(&Ksum[(b*NH + h)*HD + (l>>4)*4 + r], ksacc[hh][r]);
        }
    }
}

// ---------------------------------------------------------------------------
// Pass B: q proj (swapped), Z in registers (shfl butterfly), V_new (hi/lo KV),
//         out proj -> float4 stores.  2048 blocks x 64 tokens. LDS 32KB.
// ---------------------------------------------------------------------------
__global__ __launch_bounds__(256, 4) void passB(
    const float* __restrict__ Q,
    const float* __restrict__ bq, const float* __restrict__ bo,
    const short* __restrict__ WqA, const short* __restrict__ WoA,
    const float* __restrict__ KV, const float* __restrict__ Ksum,
    float* __restrict__ out)
{
    __shared__ __align__(16) short QV[64*128];   // Qlds, then aliased as Vn
    __shared__ __align__(16) short Pq[64*128];

    const int t = threadIdx.x;
    const int w = t >> 6, l = t & 63;
    const int b  = blockIdx.x / BPB_B;
    const int bb = blockIdx.x % BPB_B;
    const long tok0 = (long)b * SEQ + (long)bb * CH;
    const int h0 = w * 2;

    bf16x8 wq[2][4], wo[2][4];
#pragma unroll
    for (int m = 0; m < 2; ++m)
#pragma unroll
        for (int kt = 0; kt < 4; ++kt) {
            wq[m][kt] = *(const bf16x8*)&WqA[(((w*2+m)*4 + kt)*64 + l)*8];
            wo[m][kt] = *(const bf16x8*)&WoA[(((w*2+m)*4 + kt)*64 + l)*8];
        }
    float bqv[2][4], bov[2][4], Ks[2][4];
#pragma unroll
    for (int m = 0; m < 2; ++m)
#pragma unroll
        for (int r = 0; r < 4; ++r) {
            int cc = (w*2+m)*16 + (l>>4)*4 + r;
            bqv[m][r] = bq[cc];
            bov[m][r] = bo[cc];
            Ks[m][r]  = Ksum[b*NH*HD + cc];
        }

    // KV^T hi/lo A-frags for this wave's 2 heads (lanes < 32 hold k=d)
    bf16x8 kvhi[2], kvlo[2];
#pragma unroll
    for (int hh = 0; hh < 2; ++hh) {
        union { u32x4 u; bf16x8 h; } phi_, plo_;
        phi_.u = u32x4{0,0,0,0}; plo_.u = u32x4{0,0,0,0};
        if (l < 32) {
            unsigned hiw[8], low[8];
#pragma unroll
            for (int j = 0; j < 8; ++j) {
                int d = (l>>4)*8 + j, m = l & 15;
                float x = KV[((b*NH + h0+hh)*HD + d)*HD + m];
                unsigned short hs = bf16rn(x);
                unsigned short ls = bf16rn(x - bf16tof((short)hs));
                hiw[j] = hs; low[j] = ls;
            }
            phi_.u = u32x4{hiw[0]|(hiw[1]<<16), hiw[2]|(hiw[3]<<16), hiw[4]|(hiw[5]<<16), hiw[6]|(hiw[7]<<16)};
            plo_.u = u32x4{low[0]|(low[1]<<16), low[2]|(low[3]<<16), low[4]|(low[5]<<16), low[6]|(low[7]<<16)};
        }
        kvhi[hh] = phi_.h; kvlo[hh] = plo_.h;
    }

    // --- stage Q ---
#pragma unroll
    for (int i = 0; i < 4; ++i) {
        int lin = i*256 + t;
        int row = lin >> 4;
        int c0  = (lin & 15) * 8;
        const float4* gp = (const float4*)&Q[(tok0 + row)*D + c0];
        float4 a = gp[0], d4 = gp[1];
        u32x4 p = u32x4{cvt2(a.x,a.y), cvt2(a.z,a.w), cvt2(d4.x,d4.y), cvt2(d4.z,d4.w)};
        *(u32x4*)&QV[swzQ(row, c0)] = p;
    }
    __syncthreads();                               // bar1: Qlds ready

    // --- q-projection, swapped: C[qcol][tok]; phi; Z-partials in regs ---
    float zp[2][4];
#pragma unroll
    for (int nt = 0; nt < 4; ++nt) {
        bf16x8 qf[4];
#pragma unroll
        for (int kt = 0; kt < 4; ++kt)
            qf[kt] = *(bf16x8*)&QV[swzQ(nt*16 + (l&15), kt*32 + (l>>4)*8)];
#pragma unroll
        for (int m = 0; m < 2; ++m) {
            f32x4 acc = f32x4{bqv[m][0], bqv[m][1], bqv[m][2], bqv[m][3]};
#pragma unroll
            for (int kt = 0; kt < 4; ++kt)
                acc = MFMA16(wq[m][kt], qf[kt], acc);
            // phi, round to bf16, use rounded values for BOTH numerator & Z
            unsigned short s[4];
            float zacc = 0.f;
#pragma unroll
            for (int r = 0; r < 4; ++r) {
                float x = acc[r];
                x = (x > 0.f) ? (x + 1.f) : __expf(x);
                s[r] = bf16rn(x);
                zacc += bf16tof((short)s[r]) * Ks[m][r];
            }
            zp[m][nt] = zacc;
            int tok = nt*16 + (l & 15);
            int qc  = (w*2+m)*16 + (l>>4)*4;
            u32x2 p = u32x2{ (unsigned)s[0] | ((unsigned)s[1]<<16),
                             (unsigned)s[2] | ((unsigned)s[3]<<16) };
            *(u32x2*)&Pq[swzQ(tok, qc)] = p;
        }
    }
    // butterfly reduce over the 4 lane-groups (l^16, l^32) -> full denominator
    float z[2][4];
#pragma unroll
    for (int m = 0; m < 2; ++m)
#pragma unroll
        for (int nt = 0; nt < 4; ++nt) {
            float s = zp[m][nt];
            s += __shfl_xor(s, 16, 64);
            s += __shfl_xor(s, 32, 64);
            z[m][nt] = 1.f / (s + EPS_);
        }
    __syncthreads();                               // bar2: Pq ready

    // --- V_new, swapped per head: C[vcol][tok]; scale by z; write Vn(=QV) ---
#pragma unroll
    for (int hh = 0; hh < 2; ++hh) {
        int h = h0 + hh;
#pragma unroll
        for (int nt = 0; nt < 4; ++nt) {
            union { u32x4 u; bf16x8 h8; } pf; pf.u = u32x4{0,0,0,0};
            if (l < 32)
                pf.h8 = *(bf16x8*)&Pq[swzQ(nt*16 + (l&15), h*16 + (l>>4)*8)];
            f32x4 vn = {0.f,0.f,0.f,0.f};
            vn = MFMA16(kvhi[hh], pf.h8, vn);
            vn = MFMA16(kvlo[hh], pf.h8, vn);
            float zz = z[hh][nt];
            int tok = nt*16 + (l & 15);
            int vc  = h*16 + (l>>4)*4;
            u32x2 p = u32x2{cvt2(vn[0]*zz, vn[1]*zz), cvt2(vn[2]*zz, vn[3]*zz)};
            *(u32x2*)&QV[swzQ(tok, vc)] = p;
        }
    }
    __syncthreads();                               // bar3: Vn ready

    // --- out-projection, swapped: C[outcol][tok] -> global float4 ---
#pragma unroll
    for (int nt = 0; nt < 4; ++nt) {
        bf16x8 vf[4];
#pragma unroll
        for (int kt = 0; kt < 4; ++kt)
            vf[kt] = *(bf16x8*)&QV[swzQ(nt*16 + (l&15), kt*32 + (l>>4)*8)];
#pragma unroll
        for (int m = 0; m < 2; ++m) {
            f32x4 oa = f32x4{bov[m][0], bov[m][1], bov[m][2], bov[m][3]};
#pragma unroll
            for (int kt = 0; kt < 4; ++kt)
                oa = MFMA16(wo[m][kt], vf[kt], oa);
            int tok = nt*16 + (l & 15);
            int oc  = (w*2+m)*16 + (l>>4)*4;
            *(float4*)&out[(tok0 + tok)*D + oc] = float4{oa[0], oa[1], oa[2], oa[3]};
        }
    }
}

extern "C" void kernel_launch(void* const* d_in, const int* in_sizes, int n_in,
                              void* d_out, int out_size, void* d_ws, size_t ws_size,
                              hipStream_t stream) {
    (void)in_sizes; (void)n_in; (void)out_size; (void)ws_size;
    const float* Q  = (const float*)d_in[0];
    const float* Wq = (const float*)d_in[1];
    const float* bq = (const float*)d_in[2];
    const float* Wk = (const float*)d_in[3];
    const float* bk = (const float*)d_in[4];
    const float* Wv = (const float*)d_in[5];
    const float* bv = (const float*)d_in[6];
    const float* Wo = (const float*)d_in[7];
    const float* bo = (const float*)d_in[8];
    float* out = (float*)d_out;

    float* KV   = (float*)d_ws;          // 16384 f32
    float* Ksum = KV + 16384;            // 1024 f32
    short* WB   = (short*)(Ksum + 1024); // 32768 bf16
    short* WqA  = WB + 32768;            // 16384 bf16
    short* WoA  = WqA + 16384;           // 16384 bf16

    hipMemsetAsync(d_ws, 0, (16384 + 1024)*sizeof(float), stream);
    packW<<<dim3(32),  dim3(256), 0, stream>>>(Wk, Wv, Wq, Wo, WB, WqA, WoA);
    passA<<<dim3(BS*BPB_A), dim3(256), 0, stream>>>(Q, bk, bv, WB, KV, Ksum);
    passB<<<dim3(BS*BPB_B), dim3(256), 0, stream>>>(Q, bq, bo, WqA, WoA, KV, Ksum, out);
}